// Round 8
// baseline (31.709 us; speedup 1.0000x reference)
//
#include <hip/hip_runtime.h>
#include <math.h>

#define RES 128
#define TOPK 16
#define NPTS 192
#define NQ 64                    // 4 tasks * 16 points
#define SIGMA_F (6.0f / 128.0f)
#define INV2S2 (1.0f / (2.0f * SIGMA_F * SIGMA_F))
#define GPITCH 132               // G row pitch in floats (128 + 4 pad)
#define NBLK 4                   // blocks (CUs)
#define NTHR 1024                // 16 waves, 4 per SIMD
#define CTR_OFF 8                // u32 index of done-counter in ws
#define IPART_OFF 16             // float idx: I partials [16..19], S1=20, S2=21

// ---------------------------------------------------------------------------
// Micro-kernel: zero the done-counter (ws is poisoned once; we re-zero per call).
// ---------------------------------------------------------------------------
__global__ void iou_zero(unsigned* __restrict__ ws_u) { ws_u[CTR_OFF] = 0u; }

// ---------------------------------------------------------------------------
// Separable IoU, 4 CUs:
//   I  = sum_{q,q'} Cx[q][q'] Cy[q][q'] Cz[q][q'],  C*[q][q'] = <G*[q], G*[q']>
//   S1 = sum_q Sx Sy Sz (tasks 0,1), S2 likewise (tasks 2,3); w folded into Gx.
// Work slot = (pair, slice): 512 cross pairs x 8 slices of 16 grid columns.
// Per axis: build G[64][128] in LDS (redundant per block), slice-partial dots,
// 3-stage shfl_xor (1,2,4) -> full axis dot per 8-lane group, THEN multiply
// into the cross-axis product. Block 0's first 512 threads also do self-sums.
// Combine: partials -> ws, threadfence+atomic counter, last block finishes.
// task: 0 = set1/b0, 1 = set1/b1, 2 = set2/b0, 3 = set2/b1
// ---------------------------------------------------------------------------
__global__ __launch_bounds__(NTHR) void iou_sep(
    const float* __restrict__ pts1, const float* __restrict__ w1,
    const float* __restrict__ pts2, const float* __restrict__ w2,
    float* __restrict__ ws, float* __restrict__ out)
{
    __shared__ float Gf[NQ * GPITCH];   // 33.8 KB, rebuilt per axis
    __shared__ float swall[4][NPTS];
    __shared__ float sval[4][TOPK];
    __shared__ int   sidx[4][TOPK];
    __shared__ float sp[NQ][3];
    __shared__ float sw[NQ];
    __shared__ float sbound[6];         // lo x,y,z ; hi x,y,z
    __shared__ float rI[16];
    __shared__ float rS[8];

    const int tid  = threadIdx.x;
    const int lane = tid & 63;
    const int wid  = tid >> 6;

    // ---- phase 1: rank-based top-16; waves 0-3, wave == task ----
    float v0 = 0.0f, v1 = 0.0f, v2 = 0.0f;
    const float* pts = nullptr;
    if (wid < 4) {
        const int set = wid >> 1;
        const int b   = wid & 1;
        const float* w = (set ? w2 : w1) + b * NPTS;
        pts = (set ? pts2 : pts1) + b * NPTS * 3;
        v0 = w[lane];
        v1 = w[lane + 64];
        v2 = w[lane + 128];
        swall[wid][lane]       = v0;
        swall[wid][lane + 64]  = v1;
        swall[wid][lane + 128] = v2;
    }
    __syncthreads();

    if (wid < 4) {
        // rank among all 192: strictly-greater, or equal with lower index
        int r0 = 0, r1 = 0, r2 = 0;
        for (int j = 0; j < NPTS; ++j) {
            const float wj = swall[wid][j];
            r0 += (wj > v0) || (wj == v0 && j < lane);
            r1 += (wj > v1) || (wj == v1 && j < lane + 64);
            r2 += (wj > v2) || (wj == v2 && j < lane + 128);
        }
        if (r0 < TOPK) { sval[wid][r0] = v0; sidx[wid][r0] = lane; }
        if (r1 < TOPK) { sval[wid][r1] = v1; sidx[wid][r1] = lane + 64; }
        if (r2 < TOPK) { sval[wid][r2] = v2; sidx[wid][r2] = lane + 128; }
    }
    __syncthreads();

    if (wid < 4) {
        // renormalize + gather selected points
        float v = (lane < TOPK) ? sval[wid][lane] : 0.0f;
        float s = v;
        #pragma unroll
        for (int m = 32; m; m >>= 1) s += __shfl_xor(s, m, 64);
        if (lane < TOPK) {
            const int q   = wid * TOPK + lane;
            const int idx = sidx[wid][lane];
            sw[q]    = v / (s + 1e-5f);
            sp[q][0] = pts[idx * 3 + 0];
            sp[q][1] = pts[idx * 3 + 1];
            sp[q][2] = pts[idx * 3 + 2];
        }
    }
    __syncthreads();

    // ---- phase 2: per-axis bounds over all 64 selected points ----
    if (tid < 6) {
        const int  axis  = tid % 3;
        const bool ismax = tid >= 3;
        float r = sp[0][axis];
        for (int q = 1; q < NQ; ++q) {
            const float v = sp[q][axis];
            r = ismax ? fmaxf(r, v) : fminf(r, v);
        }
        sbound[tid] = ismax ? (r + 3.0f * SIGMA_F) : (r - 3.0f * SIGMA_F);
    }
    __syncthreads();

    // ---- phase 3: per-axis build + sliced dots, multiplicative accumulate --
    // pair in [0,512): batch = pair>>8, ql = (pair>>4)&15, qr = pair&15
    // wave's 8 pairs are consecutive -> qa uniform per 8-pair group (broadcast)
    const int pair = blockIdx.x * 128 + (tid >> 3);
    const int s    = tid & 7;                       // column slice
    const int batch = pair >> 8;
    const int qa = batch * 16 + ((pair >> 4) & 15); // set1 row
    const int qb = 32 + batch * 16 + (pair & 15);   // set2 row
    const bool doSelf = (blockIdx.x == 0) && (tid < 512);
    const int  srow   = tid >> 3;                   // self-sum row (block 0)

    float cp = 1.0f;                 // cross-dot product across axes
    float sprod = 1.0f;              // self-sum product across axes

    #pragma unroll 1
    for (int axis = 0; axis < 3; ++axis) {
        // build G[q][i] (w folded in at axis 0); 8 entries per thread
        const float lo   = sbound[axis];
        const float step = (sbound[axis + 3] - lo) * (1.0f / 127.0f);
        for (int e = tid; e < NQ * RES; e += NTHR) {
            const int q = e >> 7;
            const int i = e & 127;
            const float c = lo + (float)i * step;
            const float d = c - sp[q][axis];
            float g = __expf(-d * d * INV2S2);
            if (axis == 0) g *= sw[q];
            Gf[q * GPITCH + i] = g;
        }
        __syncthreads();

        // cross dot: 16 columns (4 float4s) per thread, then 3-stage combine
        {
            const float4* A = (const float4*)&Gf[qa * GPITCH];
            const float4* B = (const float4*)&Gf[qb * GPITCH];
            float4 a = {0, 0, 0, 0};
            #pragma unroll
            for (int c = 0; c < 4; ++c) {
                const float4 x = A[s * 4 + c];
                const float4 y = B[s * 4 + c];
                a.x += x.x * y.x; a.y += x.y * y.y;
                a.z += x.z * y.z; a.w += x.w * y.w;
            }
            float d = (a.x + a.y) + (a.z + a.w);
            d += __shfl_xor(d, 1, 64);   // combine 8 slices -> full axis dot
            d += __shfl_xor(d, 2, 64);
            d += __shfl_xor(d, 4, 64);
            cp *= d;                     // full dot BEFORE cross-axis multiply
        }
        // self sums (block 0, rows 0..63 x 8 slices)
        if (doSelf) {
            const float4* A = (const float4*)&Gf[srow * GPITCH];
            float4 a = {0, 0, 0, 0};
            #pragma unroll
            for (int c = 0; c < 4; ++c) {
                const float4 x = A[s * 4 + c];
                a.x += x.x; a.y += x.y; a.z += x.z; a.w += x.w;
            }
            float d = (a.x + a.y) + (a.z + a.w);
            d += __shfl_xor(d, 1, 64);
            d += __shfl_xor(d, 2, 64);
            d += __shfl_xor(d, 4, 64);
            sprod *= d;
        }
        __syncthreads();   // protect Gf before next axis overwrites
    }

    // ---- phase 4: block reduce + cross-block combine ----
    float Ic = (s == 0) ? cp : 0.0f;      // one slice-rep per pair
    #pragma unroll
    for (int m = 32; m; m >>= 1) Ic += __shfl_xor(Ic, m, 64);
    if (lane == 0) rI[wid] = Ic;

    float Sc = (doSelf && s == 0) ? sprod : 0.0f;
    #pragma unroll
    for (int m = 32; m; m >>= 1) Sc += __shfl_xor(Sc, m, 64);
    if (lane == 0 && wid < 8) rS[wid] = Sc;   // rows 8w..8w+7
    __syncthreads();

    if (tid == 0) {
        float Ip = 0.0f;
        #pragma unroll
        for (int w = 0; w < 16; ++w) Ip += rI[w];
        ws[IPART_OFF + blockIdx.x] = Ip;
        if (blockIdx.x == 0) {
            // waves 0..3 = rows 0..31 = tasks 0,1 (set1); 4..7 = set2
            ws[IPART_OFF + 4] = (rS[0] + rS[1]) + (rS[2] + rS[3]);  // S1
            ws[IPART_OFF + 5] = (rS[4] + rS[5]) + (rS[6] + rS[7]);  // S2
        }
        __threadfence();                              // release partials
        const unsigned old = atomicAdd((unsigned*)ws + CTR_OFF, 1u);
        if (old == NBLK - 1u) {                       // last block finishes
            __threadfence();                          // acquire partials
            const float I = (ws[IPART_OFF + 0] + ws[IPART_OFF + 1])
                          + (ws[IPART_OFF + 2] + ws[IPART_OFF + 3]);
            const float U = ws[IPART_OFF + 4] + ws[IPART_OFF + 5] - I + 1e-5f;
            out[0] = 1.0f - I / U;
        }
    }
}

extern "C" void kernel_launch(void* const* d_in, const int* in_sizes, int n_in,
                              void* d_out, int out_size, void* d_ws, size_t ws_size,
                              hipStream_t stream)
{
    const float* pts1 = (const float*)d_in[0];   // [2,192,3]
    const float* w1   = (const float*)d_in[1];   // [2,192]
    const float* pts2 = (const float*)d_in[2];   // [2,192,3]
    const float* w2   = (const float*)d_in[3];   // [2,192]
    float* out = (float*)d_out;                  // scalar
    float* ws  = (float*)d_ws;

    iou_zero<<<1, 1, 0, stream>>>((unsigned*)ws);
    iou_sep<<<NBLK, NTHR, 0, stream>>>(pts1, w1, pts2, w2, ws, out);
}

// Round 9
// 24.880 us; speedup vs baseline: 1.2745x; 1.2745x over previous
//
#include <hip/hip_runtime.h>
#include <math.h>

#define RES 128
#define TOPK 16
#define NPTS 192
#define NQ 64                    // 4 tasks * 16 points
#define SIGMA_F (6.0f / 128.0f)
#define INV2S2 (1.0f / (2.0f * SIGMA_F * SIGMA_F))
#define GPITCH 132               // G row pitch in floats (128 + 4 pad)
#define NBLK 8                   // blocks (CUs)
#define NTHR 1024                // 16 waves, 4 per SIMD
#define CTR_OFF 8                // u32 index of done-counter in ws
#define IPART_OFF 16             // float idx: I partials [16..23], S1=24, S2=25

// ---------------------------------------------------------------------------
// Micro-kernel: zero the done-counter (ws poisoned once; re-zero every call).
// ---------------------------------------------------------------------------
__global__ void iou_zero(unsigned* __restrict__ ws_u) { ws_u[CTR_OFF] = 0u; }

// ---------------------------------------------------------------------------
// Separable IoU:
//   I  = sum_{q,q'} Cx[q][q'] Cy[q][q'] Cz[q][q'],  C*[q][q'] = <G*[q],G*[q']>
//   S1 = sum_q Sx Sy Sz (tasks 0,1), S2 likewise (tasks 2,3); w folded into Gx.
// R9 changes (latency-chain kill):
//   - rank: 768 threads, 1 per (task,element), unroll 16 -> batched LDS loads
//   - bounds: wave-parallel shfl_xor min/max (was 63-iter serial loop)
//   - dots: 8 blocks, slice-16 per pair (2+2 b128 reads + 4-stage shfl)
// task: 0 = set1/b0, 1 = set1/b1, 2 = set2/b0, 3 = set2/b1
// ---------------------------------------------------------------------------
__global__ __launch_bounds__(NTHR) void iou_sep(
    const float* __restrict__ pts1, const float* __restrict__ w1,
    const float* __restrict__ pts2, const float* __restrict__ w2,
    float* __restrict__ ws, float* __restrict__ out)
{
    __shared__ float Gf[NQ * GPITCH];   // 33.8 KB, rebuilt per axis
    __shared__ float swall[4][NPTS];
    __shared__ float sval[4][TOPK];
    __shared__ int   sidx[4][TOPK];
    __shared__ float sp[NQ][3];
    __shared__ float sw[NQ];
    __shared__ float sbound[6];         // lo x,y,z ; hi x,y,z
    __shared__ float rI[16], rS[16], rT[16];

    const int tid  = threadIdx.x;
    const int lane = tid & 63;
    const int wid  = tid >> 6;

    // ---- phase A: load all 4x192 weights -> LDS (1 per thread, wid<12) ----
    float myv = 0.0f;
    int mytask = 0, myelem = 0;
    if (wid < 12) {
        mytask = wid / 3;                          // 3 waves per task
        myelem = (wid - mytask * 3) * 64 + lane;   // 0..191
        const int set = mytask >> 1;
        const int b   = mytask & 1;
        const float* w = (set ? w2 : w1) + b * NPTS;
        myv = w[myelem];
        swall[mytask][myelem] = myv;
    }
    __syncthreads();

    // ---- phase B: rank among 192 (strict >, or == with lower index) ----
    // unroll 16 -> 16 independent LDS loads in flight per batch
    if (wid < 12) {
        int r = 0;
        #pragma unroll 16
        for (int j = 0; j < NPTS; ++j) {
            const float wj = swall[mytask][j];
            r += (wj > myv) || (wj == myv && j < myelem);
        }
        if (r < TOPK) { sval[mytask][r] = myv; sidx[mytask][r] = myelem; }
    }
    __syncthreads();

    // ---- phase C: renormalize + gather selected points (waves 0-3) ----
    if (wid < 4) {
        const int set = wid >> 1;
        const int b   = wid & 1;
        const float* pts = (set ? pts2 : pts1) + b * NPTS * 3;
        float v = (lane < TOPK) ? sval[wid][lane] : 0.0f;
        float s = v;
        #pragma unroll
        for (int m = 32; m; m >>= 1) s += __shfl_xor(s, m, 64);
        if (lane < TOPK) {
            const int q   = wid * TOPK + lane;
            const int idx = sidx[wid][lane];
            sw[q]    = v / (s + 1e-5f);
            sp[q][0] = pts[idx * 3 + 0];
            sp[q][1] = pts[idx * 3 + 1];
            sp[q][2] = pts[idx * 3 + 2];
        }
    }
    __syncthreads();

    // ---- phase D: bounds, wave-parallel (wave 0, lane = point) ----
    if (wid == 0) {
        const float bx = sp[lane][0], by = sp[lane][1], bz = sp[lane][2];
        float nx = bx, Xx = bx, ny = by, Xy = by, nz = bz, Xz = bz;
        #pragma unroll
        for (int m = 32; m; m >>= 1) {
            nx = fminf(nx, __shfl_xor(nx, m, 64));
            Xx = fmaxf(Xx, __shfl_xor(Xx, m, 64));
            ny = fminf(ny, __shfl_xor(ny, m, 64));
            Xy = fmaxf(Xy, __shfl_xor(Xy, m, 64));
            nz = fminf(nz, __shfl_xor(nz, m, 64));
            Xz = fmaxf(Xz, __shfl_xor(Xz, m, 64));
        }
        if (lane == 0) {
            sbound[0] = nx - 3.0f * SIGMA_F;
            sbound[1] = ny - 3.0f * SIGMA_F;
            sbound[2] = nz - 3.0f * SIGMA_F;
            sbound[3] = Xx + 3.0f * SIGMA_F;
            sbound[4] = Xy + 3.0f * SIGMA_F;
            sbound[5] = Xz + 3.0f * SIGMA_F;
        }
    }
    __syncthreads();

    // ---- phase E: per-axis build + sliced dots ----
    // slot: pr = tid>>4 (pair-slot / self-row), s = tid&15 (8-col slice)
    const int pr   = tid >> 4;
    const int s    = tid & 15;
    const int pair = blockIdx.x * 64 + pr;          // [0, 512)
    const int batch = pair >> 8;
    const int qa = batch * 16 + ((pair >> 4) & 15); // set1 row
    const int qb = 32 + batch * 16 + (pair & 15);   // set2 row
    const bool doSelf = (blockIdx.x == 0);

    float cp = 1.0f, sprod = 1.0f;

    #pragma unroll 1
    for (int axis = 0; axis < 3; ++axis) {
        // build G[q][i] (w folded in at axis 0); exactly 8 entries/thread
        const float lo   = sbound[axis];
        const float step = (sbound[axis + 3] - lo) * (1.0f / 127.0f);
        #pragma unroll
        for (int k = 0; k < 8; ++k) {
            const int e = tid + k * NTHR;
            const int q = e >> 7;
            const int i = e & 127;
            const float c = lo + (float)i * step;
            const float d = c - sp[q][axis];
            float g = __expf(-d * d * INV2S2);
            if (axis == 0) g *= sw[q];
            Gf[q * GPITCH + i] = g;
        }
        __syncthreads();

        // cross dot: 8 columns (2 float4 per row) + 4-stage slice combine
        {
            const float4* A = (const float4*)&Gf[qa * GPITCH + s * 8];
            const float4* B = (const float4*)&Gf[qb * GPITCH + s * 8];
            const float4 x0 = A[0], x1 = A[1];
            const float4 y0 = B[0], y1 = B[1];
            float d = (x0.x * y0.x + x0.y * y0.y) + (x0.z * y0.z + x0.w * y0.w)
                    + (x1.x * y1.x + x1.y * y1.y) + (x1.z * y1.z + x1.w * y1.w);
            d += __shfl_xor(d, 1, 64);
            d += __shfl_xor(d, 2, 64);
            d += __shfl_xor(d, 4, 64);
            d += __shfl_xor(d, 8, 64);
            cp *= d;                    // full axis dot, then cross-axis product
        }
        // self sums (block 0 only): row pr, same slicing
        if (doSelf) {
            const float4* A = (const float4*)&Gf[pr * GPITCH + s * 8];
            const float4 x0 = A[0], x1 = A[1];
            float d = (x0.x + x0.y) + (x0.z + x0.w)
                    + (x1.x + x1.y) + (x1.z + x1.w);
            d += __shfl_xor(d, 1, 64);
            d += __shfl_xor(d, 2, 64);
            d += __shfl_xor(d, 4, 64);
            d += __shfl_xor(d, 8, 64);
            sprod *= d;
        }
        __syncthreads();   // protect Gf before next axis overwrites
    }

    // ---- phase F: block reduce + cross-block combine ----
    float Ic = (s == 0) ? cp : 0.0f;      // one rep per pair
    #pragma unroll
    for (int m = 32; m; m >>= 1) Ic += __shfl_xor(Ic, m, 64);
    if (lane == 0) rI[wid] = Ic;

    float S1c = (doSelf && s == 0 && pr < 32) ? sprod : 0.0f;   // tasks 0,1
    float S2c = (doSelf && s == 0 && pr >= 32) ? sprod : 0.0f;  // tasks 2,3
    #pragma unroll
    for (int m = 32; m; m >>= 1) {
        S1c += __shfl_xor(S1c, m, 64);
        S2c += __shfl_xor(S2c, m, 64);
    }
    if (lane == 0) { rS[wid] = S1c; rT[wid] = S2c; }
    __syncthreads();

    if (tid == 0) {
        float Ip = 0.0f;
        #pragma unroll
        for (int w = 0; w < 16; ++w) Ip += rI[w];
        ws[IPART_OFF + blockIdx.x] = Ip;
        if (blockIdx.x == 0) {
            float S1 = 0.0f, S2 = 0.0f;
            #pragma unroll
            for (int w = 0; w < 16; ++w) { S1 += rS[w]; S2 += rT[w]; }
            ws[IPART_OFF + 8] = S1;
            ws[IPART_OFF + 9] = S2;
        }
        __threadfence();                              // release partials
        const unsigned old = atomicAdd((unsigned*)ws + CTR_OFF, 1u);
        if (old == NBLK - 1u) {                       // last block finalizes
            __threadfence();                          // acquire partials
            float I = 0.0f;
            #pragma unroll
            for (int b = 0; b < NBLK; ++b) I += ws[IPART_OFF + b];
            const float U = ws[IPART_OFF + 8] + ws[IPART_OFF + 9] - I + 1e-5f;
            out[0] = 1.0f - I / U;
        }
    }
}

extern "C" void kernel_launch(void* const* d_in, const int* in_sizes, int n_in,
                              void* d_out, int out_size, void* d_ws, size_t ws_size,
                              hipStream_t stream)
{
    const float* pts1 = (const float*)d_in[0];   // [2,192,3]
    const float* w1   = (const float*)d_in[1];   // [2,192]
    const float* pts2 = (const float*)d_in[2];   // [2,192,3]
    const float* w2   = (const float*)d_in[3];   // [2,192]
    float* out = (float*)d_out;                  // scalar
    float* ws  = (float*)d_ws;

    iou_zero<<<1, 1, 0, stream>>>((unsigned*)ws);
    iou_sep<<<NBLK, NTHR, 0, stream>>>(pts1, w1, pts2, w2, ws, out);
}

// Round 10
// 23.058 us; speedup vs baseline: 1.3752x; 1.0790x over previous
//
#include <hip/hip_runtime.h>
#include <math.h>

#define RES 128
#define TOPK 16
#define NPTS 192
#define NQ 64                    // 4 tasks * 16 points
#define SIGMA_F (6.0f / 128.0f)
#define INV2S2 (1.0f / (2.0f * SIGMA_F * SIGMA_F))
#define GPITCH 132               // G row pitch in floats (128 + 4 pad)
#define NBLK 8                   // blocks (CUs)
#define NTHR 1024                // 16 waves, 4 per SIMD
#define CTR_OFF 8                // u32 index of done-counter in ws
#define IPART_OFF 16             // float idx: I partials [16..23], S1=24, S2=25

// ---------------------------------------------------------------------------
// Separable IoU:
//   I  = sum_{q,q'} Cx[q][q'] Cy[q][q'] Cz[q][q'],  C*[q][q'] = <G*[q],G*[q']>
//   S1 = sum_q Sx Sy Sz (tasks 0,1), S2 likewise (tasks 2,3); w folded into Gx.
// R10 changes (DS-pipe throughput + barrier kill):
//   - rank reads via float4: 48 b128/thread (was 192 b32) -> 4x fewer DS instrs
//   - build ALL 3 axes into Gf[3][..] (101KB LDS): 1 barrier, then all dots
//     stream with no intervening barriers
//   - counter zeroed by a graph memset node instead of a kernel
// task: 0 = set1/b0, 1 = set1/b1, 2 = set2/b0, 3 = set2/b1
// ---------------------------------------------------------------------------
__global__ __launch_bounds__(NTHR) void iou_sep(
    const float* __restrict__ pts1, const float* __restrict__ w1,
    const float* __restrict__ pts2, const float* __restrict__ w2,
    float* __restrict__ ws, float* __restrict__ out)
{
    __shared__ float Gf[3][NQ * GPITCH];          // 101376 B
    __shared__ __align__(16) float swall[4][NPTS]; // 3072 B, rows 16B-aligned
    __shared__ float sval[4][TOPK];
    __shared__ int   sidx[4][TOPK];
    __shared__ float sp[NQ][3];
    __shared__ float sw[NQ];
    __shared__ float sbound[6];                    // lo x,y,z ; hi x,y,z
    __shared__ float rI[16], rS[16], rT[16];

    const int tid  = threadIdx.x;
    const int lane = tid & 63;
    const int wid  = tid >> 6;

    // ---- phase A: load all 4x192 weights -> LDS (1 per thread, wid<12) ----
    float myv = 0.0f;
    int mytask = 0, myelem = 0;
    if (wid < 12) {
        mytask = wid / 3;                          // 3 waves per task
        myelem = (wid - mytask * 3) * 64 + lane;   // 0..191
        const int set = mytask >> 1;
        const int b   = mytask & 1;
        const float* w = (set ? w2 : w1) + b * NPTS;
        myv = w[myelem];
        swall[mytask][myelem] = myv;
    }
    __syncthreads();

    // ---- phase B: rank among 192 via float4 reads (strict >, tie: j<e) ----
    if (wid < 12) {
        const float4* wrow = (const float4*)swall[mytask];
        int r = 0;
        #pragma unroll
        for (int c = 0; c < NPTS / 4; ++c) {
            const float4 wv = wrow[c];
            const int jb = c * 4;
            r += (wv.x > myv) || (wv.x == myv && jb + 0 < myelem);
            r += (wv.y > myv) || (wv.y == myv && jb + 1 < myelem);
            r += (wv.z > myv) || (wv.z == myv && jb + 2 < myelem);
            r += (wv.w > myv) || (wv.w == myv && jb + 3 < myelem);
        }
        if (r < TOPK) { sval[mytask][r] = myv; sidx[mytask][r] = myelem; }
    }
    __syncthreads();

    // ---- phase C: renormalize + gather selected points (waves 0-3) ----
    if (wid < 4) {
        const int set = wid >> 1;
        const int b   = wid & 1;
        const float* pts = (set ? pts2 : pts1) + b * NPTS * 3;
        float v = (lane < TOPK) ? sval[wid][lane] : 0.0f;
        float s = v;
        #pragma unroll
        for (int m = 32; m; m >>= 1) s += __shfl_xor(s, m, 64);
        if (lane < TOPK) {
            const int q   = wid * TOPK + lane;
            const int idx = sidx[wid][lane];
            sw[q]    = v / (s + 1e-5f);
            sp[q][0] = pts[idx * 3 + 0];
            sp[q][1] = pts[idx * 3 + 1];
            sp[q][2] = pts[idx * 3 + 2];
        }
    }
    __syncthreads();

    // ---- phase D: bounds, wave-parallel (wave 0, lane = point) ----
    if (wid == 0) {
        const float bx = sp[lane][0], by = sp[lane][1], bz = sp[lane][2];
        float nx = bx, Xx = bx, ny = by, Xy = by, nz = bz, Xz = bz;
        #pragma unroll
        for (int m = 32; m; m >>= 1) {
            nx = fminf(nx, __shfl_xor(nx, m, 64));
            Xx = fmaxf(Xx, __shfl_xor(Xx, m, 64));
            ny = fminf(ny, __shfl_xor(ny, m, 64));
            Xy = fmaxf(Xy, __shfl_xor(Xy, m, 64));
            nz = fminf(nz, __shfl_xor(nz, m, 64));
            Xz = fmaxf(Xz, __shfl_xor(Xz, m, 64));
        }
        if (lane == 0) {
            sbound[0] = nx - 3.0f * SIGMA_F;
            sbound[1] = ny - 3.0f * SIGMA_F;
            sbound[2] = nz - 3.0f * SIGMA_F;
            sbound[3] = Xx + 3.0f * SIGMA_F;
            sbound[4] = Xy + 3.0f * SIGMA_F;
            sbound[5] = Xz + 3.0f * SIGMA_F;
        }
    }
    __syncthreads();

    // ---- phase E: build all 3 axis tables (w folded in at axis 0) ----
    // 3*64*128 = 24576 entries, exactly 24 per thread
    #pragma unroll
    for (int k = 0; k < 24; ++k) {
        const int e    = tid + k * NTHR;
        const int axis = e >> 13;        // / 8192
        const int rem  = e & 8191;
        const int q    = rem >> 7;
        const int i    = rem & 127;
        const float lo   = sbound[axis];
        const float step = (sbound[axis + 3] - lo) * (1.0f / 127.0f);
        const float c = lo + (float)i * step;
        const float d = c - sp[q][axis];
        float g = __expf(-d * d * INV2S2);
        if (axis == 0) g *= sw[q];
        Gf[axis][q * GPITCH + i] = g;
    }
    __syncthreads();

    // ---- phase F: sliced dots, all 3 axes back-to-back (no barriers) ----
    // slot: pr = tid>>4 (pair-slot / self-row), s = tid&15 (8-col slice)
    const int pr   = tid >> 4;
    const int s    = tid & 15;
    const int pair = blockIdx.x * 64 + pr;          // [0, 512)
    const int batch = pair >> 8;
    const int qa = batch * 16 + ((pair >> 4) & 15); // set1 row
    const int qb = 32 + batch * 16 + (pair & 15);   // set2 row
    const bool doSelf = (blockIdx.x == 0);

    float cp = 1.0f, sprod = 1.0f;

    #pragma unroll
    for (int axis = 0; axis < 3; ++axis) {
        // cross dot: 8 columns (2 float4 per row) + 4-stage slice combine
        {
            const float4* A = (const float4*)&Gf[axis][qa * GPITCH + s * 8];
            const float4* B = (const float4*)&Gf[axis][qb * GPITCH + s * 8];
            const float4 x0 = A[0], x1 = A[1];
            const float4 y0 = B[0], y1 = B[1];
            float d = (x0.x * y0.x + x0.y * y0.y) + (x0.z * y0.z + x0.w * y0.w)
                    + (x1.x * y1.x + x1.y * y1.y) + (x1.z * y1.z + x1.w * y1.w);
            d += __shfl_xor(d, 1, 64);
            d += __shfl_xor(d, 2, 64);
            d += __shfl_xor(d, 4, 64);
            d += __shfl_xor(d, 8, 64);
            cp *= d;                    // full axis dot, then cross-axis product
        }
        // self sums (block 0 only): row pr, same slicing
        if (doSelf) {
            const float4* A = (const float4*)&Gf[axis][pr * GPITCH + s * 8];
            const float4 x0 = A[0], x1 = A[1];
            float d = (x0.x + x0.y) + (x0.z + x0.w)
                    + (x1.x + x1.y) + (x1.z + x1.w);
            d += __shfl_xor(d, 1, 64);
            d += __shfl_xor(d, 2, 64);
            d += __shfl_xor(d, 4, 64);
            d += __shfl_xor(d, 8, 64);
            sprod *= d;
        }
    }

    // ---- phase G: block reduce + cross-block combine ----
    float Ic = (s == 0) ? cp : 0.0f;      // one rep per pair
    #pragma unroll
    for (int m = 32; m; m >>= 1) Ic += __shfl_xor(Ic, m, 64);
    if (lane == 0) rI[wid] = Ic;

    float S1c = (doSelf && s == 0 && pr < 32) ? sprod : 0.0f;   // tasks 0,1
    float S2c = (doSelf && s == 0 && pr >= 32) ? sprod : 0.0f;  // tasks 2,3
    #pragma unroll
    for (int m = 32; m; m >>= 1) {
        S1c += __shfl_xor(S1c, m, 64);
        S2c += __shfl_xor(S2c, m, 64);
    }
    if (lane == 0) { rS[wid] = S1c; rT[wid] = S2c; }
    __syncthreads();

    if (tid == 0) {
        float Ip = 0.0f;
        #pragma unroll
        for (int w = 0; w < 16; ++w) Ip += rI[w];
        ws[IPART_OFF + blockIdx.x] = Ip;
        if (blockIdx.x == 0) {
            float S1 = 0.0f, S2 = 0.0f;
            #pragma unroll
            for (int w = 0; w < 16; ++w) { S1 += rS[w]; S2 += rT[w]; }
            ws[IPART_OFF + 8] = S1;
            ws[IPART_OFF + 9] = S2;
        }
        __threadfence();                              // release partials
        const unsigned old = atomicAdd((unsigned*)ws + CTR_OFF, 1u);
        if (old == NBLK - 1u) {                       // last block finalizes
            __threadfence();                          // acquire partials
            float I = 0.0f;
            #pragma unroll
            for (int b = 0; b < NBLK; ++b) I += ws[IPART_OFF + b];
            const float U = ws[IPART_OFF + 8] + ws[IPART_OFF + 9] - I + 1e-5f;
            out[0] = 1.0f - I / U;
        }
    }
}

extern "C" void kernel_launch(void* const* d_in, const int* in_sizes, int n_in,
                              void* d_out, int out_size, void* d_ws, size_t ws_size,
                              hipStream_t stream)
{
    const float* pts1 = (const float*)d_in[0];   // [2,192,3]
    const float* w1   = (const float*)d_in[1];   // [2,192]
    const float* pts2 = (const float*)d_in[2];   // [2,192,3]
    const float* w2   = (const float*)d_in[3];   // [2,192]
    float* out = (float*)d_out;                  // scalar
    float* ws  = (float*)d_ws;

    // zero the done-counter via a memset node (cheaper than a kernel dispatch)
    hipMemsetAsync((char*)d_ws + CTR_OFF * sizeof(unsigned), 0,
                   sizeof(unsigned), stream);
    iou_sep<<<NBLK, NTHR, 0, stream>>>(pts1, w1, pts2, w2, ws, out);
}

// Round 11
// 15.076 us; speedup vs baseline: 2.1032x; 1.5294x over previous
//
#include <hip/hip_runtime.h>
#include <math.h>

#define RES 128
#define TOPK 16
#define NPTS 192
#define NQ 64                    // 4 tasks * 16 points
#define SIGMA_F (6.0f / 128.0f)
#define NTHR 768                 // 12 waves: one (task, element) per thread

// ---------------------------------------------------------------------------
// Analytic separable IoU. The reference's 128^3 tensor-product grid sums are
// Riemann sums of Gaussians with sigma/step >= 4.6:
//   sum_i Gq[i]*Gq'[i] = (sigma*sqrt(pi)/delta) * exp(-(pa-pb)^2/(4 sigma^2))
//       per axis (aliasing error ~exp(-pi^2*(sigma/delta)^2) ~ e-212 = 0;
//       edge truncation <= erfc(3/sqrt2)/2 ~ 1.4e-3 rel, worst case)
//   sum_i Gq[i]       = sigma*sqrt(2 pi)/delta
// =>  I  = KI * sum_{batch,q,q'} w_q w_q' exp(-D^2/(4 sigma^2)),
//     KI = sigma^3 pi^1.5 / (Dx*Dy*Dz)
//     S1+S2 = KI * 2^1.5 * sum_t W_t,   W_t = sum(v)/(sum(v)+1e-5)
//     U  = S1+S2-I+1e-5 ;  loss = 1 - I/U
// Phases: (1) rank-based top-16, one (task,element) per thread, weights
// streamed via wave-uniform reads (scalar path, no LDS); (2) wave 0: renorm +
// per-task W + bounds; (3) 512 pair exponentials; (4) tiny reduce, scalar out.
// task: 0 = set1/b0, 1 = set1/b1, 2 = set2/b0, 3 = set2/b1
// ---------------------------------------------------------------------------
__global__ __launch_bounds__(NTHR) void iou_analytic(
    const float* __restrict__ pts1, const float* __restrict__ w1,
    const float* __restrict__ pts2, const float* __restrict__ w2,
    float* __restrict__ out)
{
    __shared__ float sval[4][TOPK];
    __shared__ __align__(16) float sp4[NQ][4];   // xyz + pad (float4 reads)
    __shared__ float sw[NQ];
    __shared__ float sW[4];          // per-task sum of renormalized weights
    __shared__ float sbound[6];      // lo x,y,z ; hi x,y,z
    __shared__ float rP[12];

    const int tid  = threadIdx.x;
    const int lane = tid & 63;
    const int wid  = tid >> 6;       // 0..11

    // ---- phase 1: rank among 192 (strict >, tie: lower index) ----
    {
        const int task = wid / 3;                      // 3 waves per task
        const int elem = (wid - task * 3) * 64 + lane; // 0..191
        const int set  = task >> 1;
        const int b    = task & 1;
        const float* __restrict__ wt = (set ? w2 : w1) + b * NPTS;
        const float* __restrict__ pt = (set ? pts2 : pts1) + b * NPTS * 3;
        const float myv = wt[elem];
        int r = 0;
        #pragma unroll 16
        for (int j = 0; j < NPTS; ++j) {
            const float wj = wt[j];        // wave-uniform address -> s_load
            r += (wj > myv) || (wj == myv && j < elem);
        }
        if (r < TOPK) {                    // this element is in the top-16
            const int q = task * TOPK + r;
            sval[task][r] = myv;
            sp4[q][0] = pt[elem * 3 + 0];
            sp4[q][1] = pt[elem * 3 + 1];
            sp4[q][2] = pt[elem * 3 + 2];
            sp4[q][3] = 0.0f;
        }
    }
    __syncthreads();

    // ---- phase 2: renorm + per-task W + bounds (wave 0, lane = q) ----
    if (wid == 0) {
        const int t = lane >> 4;
        const float v = sval[t][lane & 15];
        float s = v;                       // per-16-group (per-task) sum
        s += __shfl_xor(s, 1, 64);
        s += __shfl_xor(s, 2, 64);
        s += __shfl_xor(s, 4, 64);
        s += __shfl_xor(s, 8, 64);
        const float denom = s + 1e-5f;
        sw[lane] = v / denom;
        if ((lane & 15) == 0) sW[t] = s / denom;

        // bounds over all 64 selected points
        const float px = sp4[lane][0], py = sp4[lane][1], pz = sp4[lane][2];
        float nx = px, Xx = px, ny = py, Xy = py, nz = pz, Xz = pz;
        #pragma unroll
        for (int m = 32; m; m >>= 1) {
            nx = fminf(nx, __shfl_xor(nx, m, 64));
            Xx = fmaxf(Xx, __shfl_xor(Xx, m, 64));
            ny = fminf(ny, __shfl_xor(ny, m, 64));
            Xy = fmaxf(Xy, __shfl_xor(Xy, m, 64));
            nz = fminf(nz, __shfl_xor(nz, m, 64));
            Xz = fmaxf(Xz, __shfl_xor(Xz, m, 64));
        }
        if (lane == 0) {
            sbound[0] = nx - 3.0f * SIGMA_F; sbound[3] = Xx + 3.0f * SIGMA_F;
            sbound[1] = ny - 3.0f * SIGMA_F; sbound[4] = Xy + 3.0f * SIGMA_F;
            sbound[2] = nz - 3.0f * SIGMA_F; sbound[5] = Xz + 3.0f * SIGMA_F;
        }
    }
    __syncthreads();

    // ---- phase 3: 512 cross-pair Gaussian overlaps (1 per thread) ----
    // pair = tid in [0,512): batch = tid>>8, ql = (tid>>4)&15, qr = tid&15
    float e = 0.0f;
    if (tid < 512) {
        const int batch = tid >> 8;
        const int qa = batch * 16 + ((tid >> 4) & 15);        // set1 row
        const int qb = 32 + batch * 16 + (tid & 15);          // set2 row
        const float4 pa = *(const float4*)sp4[qa];
        const float4 pb = *(const float4*)sp4[qb];
        const float dx = pa.x - pb.x;
        const float dy = pa.y - pb.y;
        const float dz = pa.z - pb.z;
        const float D2 = dx * dx + dy * dy + dz * dz;
        const float INV4S2 = 1.0f / (4.0f * SIGMA_F * SIGMA_F);
        e = sw[qa] * sw[qb] * __expf(-D2 * INV4S2);
    }
    #pragma unroll
    for (int m = 32; m; m >>= 1) e += __shfl_xor(e, m, 64);
    if (lane == 0) rP[wid] = e;
    __syncthreads();

    // ---- phase 4: finalize ----
    if (tid == 0) {
        float psum = 0.0f;
        #pragma unroll
        for (int w = 0; w < 8; ++w) psum += rP[w];    // waves 8-11 held pads
        const float Dx = (sbound[3] - sbound[0]) * (1.0f / 127.0f);
        const float Dy = (sbound[4] - sbound[1]) * (1.0f / 127.0f);
        const float Dz = (sbound[5] - sbound[2]) * (1.0f / 127.0f);
        const float s3   = SIGMA_F * SIGMA_F * SIGMA_F;
        const float PI15 = 5.5683280f;                 // pi^1.5
        const float KI   = s3 * PI15 / (Dx * Dy * Dz);
        const float KS   = KI * 2.8284271f;            // * 2^1.5
        const float I = KI * psum;
        const float S = KS * ((sW[0] + sW[1]) + (sW[2] + sW[3]));
        const float U = S - I + 1e-5f;
        out[0] = 1.0f - I / U;
    }
}

extern "C" void kernel_launch(void* const* d_in, const int* in_sizes, int n_in,
                              void* d_out, int out_size, void* d_ws, size_t ws_size,
                              hipStream_t stream)
{
    const float* pts1 = (const float*)d_in[0];   // [2,192,3]
    const float* w1   = (const float*)d_in[1];   // [2,192]
    const float* pts2 = (const float*)d_in[2];   // [2,192,3]
    const float* w2   = (const float*)d_in[3];   // [2,192]
    float* out = (float*)d_out;                  // scalar

    iou_analytic<<<1, NTHR, 0, stream>>>(pts1, w1, pts2, w2, out);
}

// Round 12
// 12.996 us; speedup vs baseline: 2.4399x; 1.1601x over previous
//
#include <hip/hip_runtime.h>
#include <math.h>

#define RES 128
#define TOPK 16
#define NPTS 192
#define NQ 64                    // 4 tasks * 16 points
#define SIGMA_F (6.0f / 128.0f)
#define NTHR 768                 // 12 waves: one (task, element) per thread

// ---------------------------------------------------------------------------
// Analytic separable IoU (validated exact-to-threshold in R11):
//   I  = KI * sum_{batch,q,q'} w_q w_q' exp(-|pa-pb|^2/(4 sigma^2)),
//   KI = sigma^3 pi^1.5 / (Dx*Dy*Dz);  S1+S2 = KI * 2^1.5 * sum_t W_t
//   U = S1+S2-I+1e-5 ;  loss = 1 - I/U
// R12 change: rank loop reads weights from LDS via float4 (uniform-address
// broadcast ds_read_b128, 48/thread) instead of 192 per-lane global loads
// (2304 texture-pipe instrs on one CU was the R11 cost driver).
// task: 0 = set1/b0, 1 = set1/b1, 2 = set2/b0, 3 = set2/b1
// ---------------------------------------------------------------------------
__global__ __launch_bounds__(NTHR) void iou_analytic(
    const float* __restrict__ pts1, const float* __restrict__ w1,
    const float* __restrict__ pts2, const float* __restrict__ w2,
    float* __restrict__ out)
{
    __shared__ __align__(16) float swall[4][NPTS];   // 3 KB staged weights
    __shared__ float sval[4][TOPK];
    __shared__ __align__(16) float sp4[NQ][4];       // xyz + pad
    __shared__ float sw[NQ];
    __shared__ float sW[4];          // per-task sum of renormalized weights
    __shared__ float sbound[6];      // lo x,y,z ; hi x,y,z
    __shared__ float rP[12];

    const int tid  = threadIdx.x;
    const int lane = tid & 63;
    const int wid  = tid >> 6;       // 0..11

    // ---- phase A: stage all 4x192 weights -> LDS (1 coalesced load each) --
    const int task = wid / 3;                       // 3 waves per task
    const int elem = (wid - task * 3) * 64 + lane;  // 0..191
    const int set  = task >> 1;
    const int b    = task & 1;
    const float* __restrict__ wt = (set ? w2 : w1) + b * NPTS;
    const float* __restrict__ pt = (set ? pts2 : pts1) + b * NPTS * 3;
    const float myv = wt[elem];
    swall[task][elem] = myv;
    __syncthreads();

    // ---- phase B: rank among 192 via float4 LDS broadcasts ----
    {
        const float4* __restrict__ wrow = (const float4*)swall[task];
        int r = 0;
        #pragma unroll
        for (int c = 0; c < NPTS / 4; ++c) {
            const float4 wv = wrow[c];   // uniform addr per wave -> broadcast
            const int jb = c * 4;
            r += (wv.x > myv) || (wv.x == myv && jb + 0 < elem);
            r += (wv.y > myv) || (wv.y == myv && jb + 1 < elem);
            r += (wv.z > myv) || (wv.z == myv && jb + 2 < elem);
            r += (wv.w > myv) || (wv.w == myv && jb + 3 < elem);
        }
        if (r < TOPK) {                  // in top-16: publish value + point
            const int q = task * TOPK + r;
            sval[task][r] = myv;
            sp4[q][0] = pt[elem * 3 + 0];
            sp4[q][1] = pt[elem * 3 + 1];
            sp4[q][2] = pt[elem * 3 + 2];
            sp4[q][3] = 0.0f;
        }
    }
    __syncthreads();

    // ---- phase C: renorm + per-task W + bounds (wave 0, lane = q) ----
    if (wid == 0) {
        const int t = lane >> 4;
        const float v = sval[t][lane & 15];
        float s = v;                     // per-16-group (per-task) sum
        s += __shfl_xor(s, 1, 64);
        s += __shfl_xor(s, 2, 64);
        s += __shfl_xor(s, 4, 64);
        s += __shfl_xor(s, 8, 64);
        const float denom = s + 1e-5f;
        sw[lane] = v / denom;
        if ((lane & 15) == 0) sW[t] = s / denom;

        // bounds over all 64 selected points
        const float px = sp4[lane][0], py = sp4[lane][1], pz = sp4[lane][2];
        float nx = px, Xx = px, ny = py, Xy = py, nz = pz, Xz = pz;
        #pragma unroll
        for (int m = 32; m; m >>= 1) {
            nx = fminf(nx, __shfl_xor(nx, m, 64));
            Xx = fmaxf(Xx, __shfl_xor(Xx, m, 64));
            ny = fminf(ny, __shfl_xor(ny, m, 64));
            Xy = fmaxf(Xy, __shfl_xor(Xy, m, 64));
            nz = fminf(nz, __shfl_xor(nz, m, 64));
            Xz = fmaxf(Xz, __shfl_xor(Xz, m, 64));
        }
        if (lane == 0) {
            sbound[0] = nx - 3.0f * SIGMA_F; sbound[3] = Xx + 3.0f * SIGMA_F;
            sbound[1] = ny - 3.0f * SIGMA_F; sbound[4] = Xy + 3.0f * SIGMA_F;
            sbound[2] = nz - 3.0f * SIGMA_F; sbound[5] = Xz + 3.0f * SIGMA_F;
        }
    }
    __syncthreads();

    // ---- phase D: 512 cross-pair Gaussian overlaps (1 per thread) ----
    float e = 0.0f;
    if (tid < 512) {
        const int batch = tid >> 8;
        const int qa = batch * 16 + ((tid >> 4) & 15);        // set1 row
        const int qb = 32 + batch * 16 + (tid & 15);          // set2 row
        const float4 pa = *(const float4*)sp4[qa];
        const float4 pb = *(const float4*)sp4[qb];
        const float dx = pa.x - pb.x;
        const float dy = pa.y - pb.y;
        const float dz = pa.z - pb.z;
        const float D2 = dx * dx + dy * dy + dz * dz;
        const float INV4S2 = 1.0f / (4.0f * SIGMA_F * SIGMA_F);
        e = sw[qa] * sw[qb] * __expf(-D2 * INV4S2);
    }
    #pragma unroll
    for (int m = 32; m; m >>= 1) e += __shfl_xor(e, m, 64);
    if (lane == 0) rP[wid] = e;
    __syncthreads();

    // ---- phase E: finalize ----
    if (tid == 0) {
        float psum = 0.0f;
        #pragma unroll
        for (int w = 0; w < 8; ++w) psum += rP[w];    // waves 8-11 held zeros
        const float Dx = (sbound[3] - sbound[0]) * (1.0f / 127.0f);
        const float Dy = (sbound[4] - sbound[1]) * (1.0f / 127.0f);
        const float Dz = (sbound[5] - sbound[2]) * (1.0f / 127.0f);
        const float s3   = SIGMA_F * SIGMA_F * SIGMA_F;
        const float PI15 = 5.5683280f;                 // pi^1.5
        const float KI   = s3 * PI15 / (Dx * Dy * Dz);
        const float KS   = KI * 2.8284271f;            // * 2^1.5
        const float I = KI * psum;
        const float S = KS * ((sW[0] + sW[1]) + (sW[2] + sW[3]));
        const float U = S - I + 1e-5f;
        out[0] = 1.0f - I / U;
    }
}

extern "C" void kernel_launch(void* const* d_in, const int* in_sizes, int n_in,
                              void* d_out, int out_size, void* d_ws, size_t ws_size,
                              hipStream_t stream)
{
    const float* pts1 = (const float*)d_in[0];   // [2,192,3]
    const float* w1   = (const float*)d_in[1];   // [2,192]
    const float* pts2 = (const float*)d_in[2];   // [2,192,3]
    const float* w2   = (const float*)d_in[3];   // [2,192]
    float* out = (float*)d_out;                  // scalar

    iou_analytic<<<1, NTHR, 0, stream>>>(pts1, w1, pts2, w2, out);
}

// Round 13
// 10.127 us; speedup vs baseline: 3.1312x; 1.2833x over previous
//
#include <hip/hip_runtime.h>
#include <math.h>

#define RES 128
#define TOPK 16
#define NPTS 192
#define NQ 64                    // 4 tasks * 16 points
#define SIGMA_F (6.0f / 128.0f)
#define NTHR 768                 // 12 waves: one (task, element) per thread

// ---------------------------------------------------------------------------
// Analytic separable IoU (validated exact-to-threshold in R11/R12):
//   I  = KI * sum_{batch,q,q'} w_q w_q' exp(-|pa-pb|^2/(4 sigma^2)),
//   KI = sigma^3 pi^1.5 / (Dx*Dy*Dz);  S1+S2 = KI * 2^1.5 * sum_t W_t
//   U = S1+S2-I+1e-5 ;  loss = 1 - I/U
// R13 change: rank loop uses STRICT-greater only (2 VALU/elem, was ~5), with
// a deterministic tie-repair pass. Strict ranks collide only for bit-equal
// weights; equal strict-rank implies equal values, and the result depends
// only on the selected SET (I is symmetric in q), so the repair (loser of
// the LDS scatter race rewrites slots r and r+1 ordered by index) restores
// exact lax.top_k semantics for tie multiplicity <= 2 (P(>2) ~ 1e-13).
// task: 0 = set1/b0, 1 = set1/b1, 2 = set2/b0, 3 = set2/b1
// ---------------------------------------------------------------------------
__global__ __launch_bounds__(NTHR) void iou_analytic(
    const float* __restrict__ pts1, const float* __restrict__ w1,
    const float* __restrict__ pts2, const float* __restrict__ w2,
    float* __restrict__ out)
{
    __shared__ __align__(16) float swall[4][NPTS];   // 3 KB staged weights
    __shared__ float sval[4][TOPK];
    __shared__ int   sidx[4][TOPK];
    __shared__ __align__(16) float sp4[NQ][4];       // xyz + pad
    __shared__ float sw[NQ];
    __shared__ float sW[4];          // per-task sum of renormalized weights
    __shared__ float sbound[6];      // lo x,y,z ; hi x,y,z
    __shared__ float rP[12];

    const int tid  = threadIdx.x;
    const int lane = tid & 63;
    const int wid  = tid >> 6;       // 0..11

    // ---- phase A: stage all 4x192 weights -> LDS (1 coalesced load each) --
    const int task = wid / 3;                       // 3 waves per task
    const int elem = (wid - task * 3) * 64 + lane;  // 0..191
    const int set  = task >> 1;
    const int b    = task & 1;
    const float* __restrict__ wt = (set ? w2 : w1) + b * NPTS;
    const float* __restrict__ pt = (set ? pts2 : pts1) + b * NPTS * 3;
    const float myv = wt[elem];
    swall[task][elem] = myv;
    __syncthreads();

    // ---- phase B: STRICT rank among 192 via float4 LDS broadcasts ----
    int r = 0;
    {
        const float4* __restrict__ wrow = (const float4*)swall[task];
        #pragma unroll
        for (int c = 0; c < NPTS / 4; ++c) {
            const float4 wv = wrow[c];   // uniform addr per wave -> broadcast
            r += (wv.x > myv);
            r += (wv.y > myv);
            r += (wv.z > myv);
            r += (wv.w > myv);
        }
        if (r < TOPK) {                  // tentative top-16: publish
            const int q = task * TOPK + r;
            sval[task][r] = myv;
            sidx[task][r] = elem;
            sp4[q][0] = pt[elem * 3 + 0];
            sp4[q][1] = pt[elem * 3 + 1];
            sp4[q][2] = pt[elem * 3 + 2];
            sp4[q][3] = 0.0f;
        }
    }
    __syncthreads();

    // ---- phase B2: tie repair (executes only on bit-equal weight ties) ----
    if (r < TOPK && sidx[task][r] != elem) {
        // I lost the scatter race at slot r -> equal-valued partner exists.
        const int surv = sidx[task][r];
        const int lo_e = (elem < surv) ? elem : surv;
        const int hi_e = (elem < surv) ? surv : elem;
        // slot r gets the lower index (lax.top_k stability)
        {
            const int q = task * TOPK + r;
            sval[task][r] = myv;
            sidx[task][r] = lo_e;
            sp4[q][0] = pt[lo_e * 3 + 0];
            sp4[q][1] = pt[lo_e * 3 + 1];
            sp4[q][2] = pt[lo_e * 3 + 2];
            sp4[q][3] = 0.0f;
        }
        if (r + 1 < TOPK) {              // higher index takes the next slot
            const int q = task * TOPK + r + 1;
            sval[task][r + 1] = myv;
            sidx[task][r + 1] = hi_e;
            sp4[q][0] = pt[hi_e * 3 + 0];
            sp4[q][1] = pt[hi_e * 3 + 1];
            sp4[q][2] = pt[hi_e * 3 + 2];
            sp4[q][3] = 0.0f;
        }
    }
    __syncthreads();

    // ---- phase C: renorm + per-task W + bounds (wave 0, lane = q) ----
    if (wid == 0) {
        const int t = lane >> 4;
        const float v = sval[t][lane & 15];
        float s = v;                     // per-16-group (per-task) sum
        s += __shfl_xor(s, 1, 64);
        s += __shfl_xor(s, 2, 64);
        s += __shfl_xor(s, 4, 64);
        s += __shfl_xor(s, 8, 64);
        const float denom = s + 1e-5f;
        sw[lane] = v / denom;
        if ((lane & 15) == 0) sW[t] = s / denom;

        // bounds over all 64 selected points
        const float px = sp4[lane][0], py = sp4[lane][1], pz = sp4[lane][2];
        float nx = px, Xx = px, ny = py, Xy = py, nz = pz, Xz = pz;
        #pragma unroll
        for (int m = 32; m; m >>= 1) {
            nx = fminf(nx, __shfl_xor(nx, m, 64));
            Xx = fmaxf(Xx, __shfl_xor(Xx, m, 64));
            ny = fminf(ny, __shfl_xor(ny, m, 64));
            Xy = fmaxf(Xy, __shfl_xor(Xy, m, 64));
            nz = fminf(nz, __shfl_xor(nz, m, 64));
            Xz = fmaxf(Xz, __shfl_xor(Xz, m, 64));
        }
        if (lane == 0) {
            sbound[0] = nx - 3.0f * SIGMA_F; sbound[3] = Xx + 3.0f * SIGMA_F;
            sbound[1] = ny - 3.0f * SIGMA_F; sbound[4] = Xy + 3.0f * SIGMA_F;
            sbound[2] = nz - 3.0f * SIGMA_F; sbound[5] = Xz + 3.0f * SIGMA_F;
        }
    }
    __syncthreads();

    // ---- phase D: 512 cross-pair Gaussian overlaps (1 per thread) ----
    float e = 0.0f;
    if (tid < 512) {
        const int batch = tid >> 8;
        const int qa = batch * 16 + ((tid >> 4) & 15);        // set1 row
        const int qb = 32 + batch * 16 + (tid & 15);          // set2 row
        const float4 pa = *(const float4*)sp4[qa];
        const float4 pb = *(const float4*)sp4[qb];
        const float dx = pa.x - pb.x;
        const float dy = pa.y - pb.y;
        const float dz = pa.z - pb.z;
        const float D2 = dx * dx + dy * dy + dz * dz;
        const float INV4S2 = 1.0f / (4.0f * SIGMA_F * SIGMA_F);
        e = sw[qa] * sw[qb] * __expf(-D2 * INV4S2);
    }
    #pragma unroll
    for (int m = 32; m; m >>= 1) e += __shfl_xor(e, m, 64);
    if (lane == 0) rP[wid] = e;
    __syncthreads();

    // ---- phase E: finalize ----
    if (tid == 0) {
        float psum = 0.0f;
        #pragma unroll
        for (int w = 0; w < 8; ++w) psum += rP[w];    // waves 8-11 held zeros
        const float Dx = (sbound[3] - sbound[0]) * (1.0f / 127.0f);
        const float Dy = (sbound[4] - sbound[1]) * (1.0f / 127.0f);
        const float Dz = (sbound[5] - sbound[2]) * (1.0f / 127.0f);
        const float s3   = SIGMA_F * SIGMA_F * SIGMA_F;
        const float PI15 = 5.5683280f;                 // pi^1.5
        const float KI   = s3 * PI15 / (Dx * Dy * Dz);
        const float KS   = KI * 2.8284271f;            // * 2^1.5
        const float I = KI * psum;
        const float S = KS * ((sW[0] + sW[1]) + (sW[2] + sW[3]));
        const float U = S - I + 1e-5f;
        out[0] = 1.0f - I / U;
    }
}

extern "C" void kernel_launch(void* const* d_in, const int* in_sizes, int n_in,
                              void* d_out, int out_size, void* d_ws, size_t ws_size,
                              hipStream_t stream)
{
    const float* pts1 = (const float*)d_in[0];   // [2,192,3]
    const float* w1   = (const float*)d_in[1];   // [2,192]
    const float* pts2 = (const float*)d_in[2];   // [2,192,3]
    const float* w2   = (const float*)d_in[3];   // [2,192]
    float* out = (float*)d_out;                  // scalar

    iou_analytic<<<1, NTHR, 0, stream>>>(pts1, w1, pts2, w2, out);
}